// Round 3
// baseline (1449.492 us; speedup 1.0000x reference)
//
#include <hip/hip_runtime.h>
#include <math.h>

#define Tsz 4096
#define Hn 16
#define DHc 128
#define DVc 128
#define CHK 1024
#define NEGV (-1e30f)
#define ROPE_C 0.14391156831f   // ln(10000)/64, exact to f32

typedef float f32x4 __attribute__((ext_vector_type(4)));
typedef short s16x8 __attribute__((ext_vector_type(8)));
typedef unsigned short u16t;
typedef u16t u16x8 __attribute__((ext_vector_type(8)));

__device__ __forceinline__ u16t f2bf(float x){
  union { float f; unsigned u; } cv; cv.f = x;
  unsigned r = cv.u + 0x7fffu + ((cv.u >> 16) & 1u);
  return (u16t)(r >> 16);
}
__device__ __forceinline__ float bf2f(u16t h){
  union { float f; unsigned u; } cv; cv.u = ((unsigned)h) << 16;
  return cv.f;
}
// Guide §3 (compile-verified on gfx950): operand type is ext_vector_type(8) short.
__device__ __forceinline__ f32x4 mfma16(u16x8 a, u16x8 b, f32x4 c){
  return __builtin_amdgcn_mfma_f32_16x16x32_bf16(
      __builtin_bit_cast(s16x8, a), __builtin_bit_cast(s16x8, b), c, 0, 0, 0);
}

// ---------------- RoPE cos/sin table: ws layout [2][Tsz][64] f32 ----------------
__global__ void rope_table_kernel(const int* __restrict__ start,
                                  float* __restrict__ tab){
  const int idx = blockIdx.x * 256 + threadIdx.x;   // 0..Tsz*64-1
  const int t = idx >> 6, d = idx & 63;
  const float inv = expf(-(float)d * ROPE_C);
  const float ang = (float)(start[0] + t) * inv;
  float s, c;
  sincosf(ang, &s, &c);
  tab[idx] = c;
  tab[Tsz * 64 + idx] = s;
}

// ---------------- fused RoPE + chunked causal flash attention ----------------
// grid: 1024 WGs = 256 problems (b,chunk,h) x 4 Q-tiles of 256 rows
// block: 512 threads = 8 waves x 32 q-rows each; KV tiles of 64 staged in LDS.
// MODE 0: cos/sin from precomputed table in d_ws. MODE 1: inline sincosf
// fallback (used only when ws_size < 2 MiB, so we never write OOB scratch).
template<int MODE>
__global__ __launch_bounds__(512, 2)
void mega_attn_kernel(const float* __restrict__ q, const float* __restrict__ k,
                      const float* __restrict__ v, const float* __restrict__ tab,
                      const int* __restrict__ start, float* __restrict__ out)
{
  // K/V hi/lo staged bf16 tiles; sP doubles as per-wave Q-staging then P-tile.
  __shared__ __align__(16) u16t sKhi[64 * 128];
  __shared__ __align__(16) u16t sKlo[64 * 128];
  __shared__ __align__(16) u16t sVhi[128 * 64];   // V^T: [dv][kv]
  __shared__ __align__(16) u16t sVlo[128 * 64];
  __shared__ __align__(16) u16t sP[8][2048];

  const int bid  = blockIdx.x;
  const int xcd  = bid & 7;          // keep same-problem q-tiles on one XCD/CU
  const int jj   = bid >> 3;
  const int prob = xcd * 32 + (jj & 31);
  const int qt   = jj >> 5;          // CU gets qt 0..3 of SAME problem -> balanced
  const int b  = prob >> 6;
  const int ch = (prob >> 4) & 3;
  const int h  = prob & 15;

  const int tid  = threadIdx.x;
  const int w    = tid >> 6;
  const int lane = tid & 63;
  const int g    = lane >> 4;
  const int lc   = lane & 15;

  const float* cosT = tab;
  const float* sinT = tab + (size_t)Tsz * 64;
  const int tab0 = ch * CHK;
  int st = 0;
  if constexpr (MODE == 1) st = start[0];

  const size_t bh = ((size_t)b * Tsz + (size_t)ch * CHK) * Hn + h;
  const float* qbase = q + bh * DHc;
  const float* kbase = k + bh * DHc;
  const float* vbase = v + bh * DVc;
  float* obase = out + bh * DVc;
  const int rs = Hn * DHc;           // 2048 elems between consecutive t

  const int qrow0 = 256 * qt + 32 * w;   // wave's first q-row within chunk
  u16t* myP = &sP[w][0];

  // ---------------- Q staging: RoPE + hi/lo split into register fragments ----
  u16x8 qhi[2][4], qlo[2][4];
  {
    const int srow = lane >> 2;      // 0..15
    const int c4   = lane & 3;       // d-range [16c4,16c4+16) and +64
    const int swz  = (srow & 7) << 3;
    #pragma unroll
    for (int rt = 0; rt < 2; ++rt){
      const int rck = qrow0 + rt * 16 + srow;
      const float* qp = qbase + (size_t)rck * rs + 16 * c4;
      f32x4 A[4], Bv[4], Cv[4], Sv[4];
      #pragma unroll
      for (int m = 0; m < 4; ++m){
        A[m]  = *(const f32x4*)(qp + 4 * m);
        Bv[m] = *(const f32x4*)(qp + 64 + 4 * m);
      }
      if constexpr (MODE == 0){
        const float* cp = cosT + (size_t)(tab0 + rck) * 64 + 16 * c4;
        const float* sp = sinT + (size_t)(tab0 + rck) * 64 + 16 * c4;
        #pragma unroll
        for (int m = 0; m < 4; ++m){
          Cv[m] = *(const f32x4*)(cp + 4 * m);
          Sv[m] = *(const f32x4*)(sp + 4 * m);
        }
      } else {
        const float pbase = (float)(st + tab0 + rck);
        #pragma unroll
        for (int m = 0; m < 16; ++m){
          const float inv = expf(-(float)(16 * c4 + m) * ROPE_C);
          float ss, cc;
          sincosf(pbase * inv, &ss, &cc);
          Cv[m >> 2][m & 3] = cc;
          Sv[m >> 2][m & 3] = ss;
        }
      }
      float r1[16], r2[16];
      u16t h1[16], h2[16];
      #pragma unroll
      for (int m = 0; m < 16; ++m){
        const float xa = A[m >> 2][m & 3];
        const float xb = Bv[m >> 2][m & 3];
        const float co = Cv[m >> 2][m & 3];
        const float si = Sv[m >> 2][m & 3];
        r1[m] = xa * co - xb * si;
        r2[m] = xb * co + xa * si;
        h1[m] = f2bf(r1[m]);
        h2[m] = f2bf(r2[m]);
      }
      u16x8 w0, w1, w2, w3;
      #pragma unroll
      for (int m = 0; m < 8; ++m){
        w0[m] = h1[m]; w1[m] = h1[m + 8];
        w2[m] = h2[m]; w3[m] = h2[m + 8];
      }
      *(u16x8*)(myP + ((srow * 128 + 16 * c4     ) ^ swz)) = w0;
      *(u16x8*)(myP + ((srow * 128 + 16 * c4 + 8 ) ^ swz)) = w1;
      *(u16x8*)(myP + ((srow * 128 + 16 * c4 + 64) ^ swz)) = w2;
      *(u16x8*)(myP + ((srow * 128 + 16 * c4 + 72) ^ swz)) = w3;
      #pragma unroll
      for (int ks = 0; ks < 4; ++ks)
        qhi[rt][ks] = *(const u16x8*)(myP + ((lc * 128 + ks * 32 + g * 8) ^ ((lc & 7) << 3)));
      #pragma unroll
      for (int m = 0; m < 8; ++m){
        w0[m] = f2bf(r1[m]     - bf2f(h1[m]));
        w1[m] = f2bf(r1[m + 8] - bf2f(h1[m + 8]));
        w2[m] = f2bf(r2[m]     - bf2f(h2[m]));
        w3[m] = f2bf(r2[m + 8] - bf2f(h2[m + 8]));
      }
      *(u16x8*)(myP + ((srow * 128 + 16 * c4     ) ^ swz)) = w0;
      *(u16x8*)(myP + ((srow * 128 + 16 * c4 + 8 ) ^ swz)) = w1;
      *(u16x8*)(myP + ((srow * 128 + 16 * c4 + 64) ^ swz)) = w2;
      *(u16x8*)(myP + ((srow * 128 + 16 * c4 + 72) ^ swz)) = w3;
      #pragma unroll
      for (int ks = 0; ks < 4; ++ks)
        qlo[rt][ks] = *(const u16x8*)(myP + ((lc * 128 + ks * 32 + g * 8) ^ ((lc & 7) << 3)));
    }
  }

  const f32x4 vzero = {0.f, 0.f, 0.f, 0.f};
  f32x4 acc[2][8];
  #pragma unroll
  for (int rt = 0; rt < 2; ++rt)
    #pragma unroll
    for (int dt = 0; dt < 8; ++dt) acc[rt][dt] = vzero;
  float mrow[8], lrow[8];
  #pragma unroll
  for (int i = 0; i < 8; ++i){ mrow[i] = -INFINITY; lrow[i] = 0.f; }

  const int ntiles = 4 * (qt + 1);
  const int krow = tid >> 3;   // 0..63 staging row
  const int kj   = tid & 7;

  for (int t = 0; t < ntiles; ++t){
    // ---- stage K tile (RoPE + hi/lo, swizzled row-major [64][128]) ----
    {
      const int kr = t * 64 + krow;
      const float* kp = kbase + (size_t)kr * rs + 8 * kj;
      f32x4 xa0 = *(const f32x4*)(kp);
      f32x4 xa1 = *(const f32x4*)(kp + 4);
      f32x4 xb0 = *(const f32x4*)(kp + 64);
      f32x4 xb1 = *(const f32x4*)(kp + 68);
      f32x4 c0, c1, s0, s1;
      if constexpr (MODE == 0){
        const float* cp = cosT + (size_t)(tab0 + kr) * 64 + 8 * kj;
        const float* sp = sinT + (size_t)(tab0 + kr) * 64 + 8 * kj;
        c0 = *(const f32x4*)(cp); c1 = *(const f32x4*)(cp + 4);
        s0 = *(const f32x4*)(sp); s1 = *(const f32x4*)(sp + 4);
      } else {
        const float pbase = (float)(st + tab0 + kr);
        #pragma unroll
        for (int m = 0; m < 8; ++m){
          const float inv = expf(-(float)(8 * kj + m) * ROPE_C);
          float ss, cc;
          sincosf(pbase * inv, &ss, &cc);
          if (m < 4){ c0[m] = cc; s0[m] = ss; }
          else      { c1[m - 4] = cc; s1[m - 4] = ss; }
        }
      }
      u16x8 hh1, ll1, hh2, ll2;
      #pragma unroll
      for (int m = 0; m < 8; ++m){
        const float xa = (m < 4) ? xa0[m & 3] : xa1[m & 3];
        const float xb = (m < 4) ? xb0[m & 3] : xb1[m & 3];
        const float co = (m < 4) ? c0[m & 3]  : c1[m & 3];
        const float si = (m < 4) ? s0[m & 3]  : s1[m & 3];
        const float r1 = xa * co - xb * si;
        const float r2 = xb * co + xa * si;
        const u16t a1h = f2bf(r1); hh1[m] = a1h; ll1[m] = f2bf(r1 - bf2f(a1h));
        const u16t a2h = f2bf(r2); hh2[m] = a2h; ll2[m] = f2bf(r2 - bf2f(a2h));
      }
      const int sw = (krow & 7) << 3;
      const int e1 = (krow * 128 + 8 * kj) ^ sw;
      const int e2 = (krow * 128 + 8 * kj + 64) ^ sw;
      *(u16x8*)(sKhi + e1) = hh1; *(u16x8*)(sKlo + e1) = ll1;
      *(u16x8*)(sKhi + e2) = hh2; *(u16x8*)(sKlo + e2) = ll2;

      // ---- stage V tile transposed (V^T [dv][kv], hi/lo) ----
      const float* vp = vbase + (size_t)(t * 64 + krow) * rs + 16 * kj;
      f32x4 v0 = *(const f32x4*)(vp);
      f32x4 v1 = *(const f32x4*)(vp + 4);
      f32x4 v2 = *(const f32x4*)(vp + 8);
      f32x4 v3 = *(const f32x4*)(vp + 12);
      #pragma unroll
      for (int m = 0; m < 16; ++m){
        const int dv = 16 * kj + m;
        const float xv = (m < 4) ? v0[m & 3] : (m < 8) ? v1[m & 3]
                        : (m < 12) ? v2[m & 3] : v3[m & 3];
        const u16t vh = f2bf(xv);
        const int ve = (dv * 64 + krow) ^ ((((dv & 7) ^ ((dv >> 3) & 7))) << 3);
        sVhi[ve] = vh;
        sVlo[ve] = f2bf(xv - bf2f(vh));
      }
    }
    __syncthreads();

    const int kmin = t * 64;
    if (kmin <= qrow0 + 31){                  // wave-level causal tile skip
      // ---- QK^T with 3-term hi/lo MFMA ----
      f32x4 S[2][4];
      #pragma unroll
      for (int ct = 0; ct < 4; ++ct){
        f32x4 s0v = vzero, s1v = vzero;
        const int krw = 16 * ct + lc;
        const int swk = (krw & 7) << 3;
        #pragma unroll
        for (int ks = 0; ks < 4; ++ks){
          const int ke = (krw * 128 + 32 * ks + 8 * g) ^ swk;
          const u16x8 bh = *(const u16x8*)(sKhi + ke);
          const u16x8 bl = *(const u16x8*)(sKlo + ke);
          s0v = mfma16(qhi[0][ks], bh, s0v);
          s0v = mfma16(qlo[0][ks], bh, s0v);
          s0v = mfma16(qhi[0][ks], bl, s0v);
          s1v = mfma16(qhi[1][ks], bh, s1v);
          s1v = mfma16(qlo[1][ks], bh, s1v);
          s1v = mfma16(qhi[1][ks], bl, s1v);
        }
        S[0][ct] = s0v; S[1][ct] = s1v;
      }
      if (kmin + 63 > qrow0){                 // diagonal tile: causal mask
        #pragma unroll
        for (int rt = 0; rt < 2; ++rt)
          #pragma unroll
          for (int ct = 0; ct < 4; ++ct){
            const int key = kmin + 16 * ct + lc;
            #pragma unroll
            for (int i = 0; i < 4; ++i){
              if (key > qrow0 + 16 * rt + 4 * g + i) S[rt][ct][i] = NEGV;
            }
          }
      }
      // ---- online softmax (rows live in 16-lane groups) ----
      #pragma unroll
      for (int rt = 0; rt < 2; ++rt){
        #pragma unroll
        for (int i = 0; i < 4; ++i){
          const int idx = rt * 4 + i;
          float tm = fmaxf(fmaxf(S[rt][0][i], S[rt][1][i]),
                           fmaxf(S[rt][2][i], S[rt][3][i]));
          tm = fmaxf(tm, __shfl_xor(tm, 1));
          tm = fmaxf(tm, __shfl_xor(tm, 2));
          tm = fmaxf(tm, __shfl_xor(tm, 4));
          tm = fmaxf(tm, __shfl_xor(tm, 8));
          const float mnew = fmaxf(mrow[idx], tm);
          const float sc = __expf(mrow[idx] - mnew);
          float ps = 0.f;
          u16t pb[4];
          #pragma unroll
          for (int ct = 0; ct < 4; ++ct){
            const float p = __expf(S[rt][ct][i] - mnew);
            ps += p;
            pb[ct] = f2bf(p);
          }
          ps += __shfl_xor(ps, 1);
          ps += __shfl_xor(ps, 2);
          ps += __shfl_xor(ps, 4);
          ps += __shfl_xor(ps, 8);
          lrow[idx] = lrow[idx] * sc + ps;
          mrow[idx] = mnew;
          #pragma unroll
          for (int dt = 0; dt < 8; ++dt) acc[rt][dt][i] *= sc;
          const int prow = 16 * rt + 4 * g + i;
          const int swp = (prow & 7) << 3;
          #pragma unroll
          for (int ct = 0; ct < 4; ++ct)
            myP[(prow * 64 + 16 * ct + lc) ^ swp] = pb[ct];
        }
      }
      // ---- PV: out += P * (Vhi + Vlo) ----
      #pragma unroll
      for (int kvs = 0; kvs < 2; ++kvs){
        const u16x8 pa0 = *(const u16x8*)(myP + ((lc * 64 + kvs * 32 + 8 * g) ^ ((lc & 7) << 3)));
        const u16x8 pa1 = *(const u16x8*)(myP + (((16 + lc) * 64 + kvs * 32 + 8 * g) ^ ((lc & 7) << 3)));
        #pragma unroll
        for (int dt = 0; dt < 8; ++dt){
          const int dv = 16 * dt + lc;
          const int ve = (dv * 64 + kvs * 32 + 8 * g) ^ (((dv & 7) ^ ((dv >> 3) & 7)) << 3);
          const u16x8 vh = *(const u16x8*)(sVhi + ve);
          const u16x8 vl = *(const u16x8*)(sVlo + ve);
          acc[0][dt] = mfma16(pa0, vh, acc[0][dt]);
          acc[0][dt] = mfma16(pa0, vl, acc[0][dt]);
          acc[1][dt] = mfma16(pa1, vh, acc[1][dt]);
          acc[1][dt] = mfma16(pa1, vl, acc[1][dt]);
        }
      }
    }
    __syncthreads();
  }

  // ---- epilogue: normalize and store ----
  #pragma unroll
  for (int rt = 0; rt < 2; ++rt){
    #pragma unroll
    for (int i = 0; i < 4; ++i){
      const int idx = rt * 4 + i;
      const float rl = 1.f / lrow[idx];
      const int rck = qrow0 + 16 * rt + 4 * g + i;
      float* op = obase + (size_t)rck * rs + lc;
      #pragma unroll
      for (int dt = 0; dt < 8; ++dt)
        op[16 * dt] = acc[rt][dt][i] * rl;
    }
  }
}

extern "C" void kernel_launch(void* const* d_in, const int* in_sizes, int n_in,
                              void* d_out, int out_size, void* d_ws, size_t ws_size,
                              hipStream_t stream) {
  const float* q = (const float*)d_in[0];
  const float* k = (const float*)d_in[1];
  const float* v = (const float*)d_in[2];
  const int* start = (const int*)d_in[3];
  float* out = (float*)d_out;
  float* tab = (float*)d_ws;   // table path needs 2 MiB: [2][4096][64] f32

  const size_t need = (size_t)2 * Tsz * 64 * sizeof(float);
  if (ws_size >= need){
    rope_table_kernel<<<dim3((Tsz * 64) / 256), dim3(256), 0, stream>>>(start, tab);
    mega_attn_kernel<0><<<dim3(1024), dim3(512), 0, stream>>>(q, k, v, tab, start, out);
  } else {
    mega_attn_kernel<1><<<dim3(1024), dim3(512), 0, stream>>>(q, k, v, tab, start, out);
  }
}